// Round 4
// baseline (17926.506 us; speedup 1.0000x reference)
//
#include <hip/hip_runtime.h>
#include <hip/hip_bf16.h>

#define Bb    128
#define Ss    256
#define Ff    4
#define Vv    1024
#define Ee    512
#define Hh    1024
#define FourH 4096
#define Mrows (Bb * Ss)
#define NBLK  96       // 32 layer-0 WGs + 64 layer-1 WGs

typedef _Float16 f16;
typedef __attribute__((ext_vector_type(8))) _Float16 half8;
typedef __attribute__((ext_vector_type(4))) float f32x4;

// ---------------------------------------------------------------------------
__global__ void cvt_f16_kernel(const float* __restrict__ s, f16* __restrict__ d, int n) {
    int i = blockIdx.x * blockDim.x + threadIdx.x;
    int stride = gridDim.x * blockDim.x;
    for (; i < n; i += stride) d[i] = (f16)s[i];
}

__global__ void bias_combine_kernel(const float* __restrict__ a, const float* __restrict__ b,
                                    const float* __restrict__ c, const float* __restrict__ d,
                                    float* __restrict__ o0, float* __restrict__ o1) {
    int i = blockIdx.x * blockDim.x + threadIdx.x;
    if (i < FourH) o0[i] = a[i] + b[i];
    else if (i < 2 * FourH) { int j = i - FourH; o1[j] = c[j] + d[j]; }
}

// Embedding: sum over F tables -> f16 [S, B, E] (time-major)
__global__ void emb_kernel(const int* __restrict__ x, const float* __restrict__ emb,
                           f16* __restrict__ out) {
    int r = blockIdx.x;
    int t = threadIdx.x;
    int b = r / Ss, s = r % Ss;
    const int* xr = x + (size_t)r * Ff;
    const float* e0 = emb + (size_t)xr[0] * Ee;
    const float* e1 = emb + (size_t)(Vv + xr[1]) * Ee;
    const float* e2 = emb + (size_t)(2 * Vv + xr[2]) * Ee;
    const float* e3 = emb + (size_t)(3 * Vv + xr[3]) * Ee;
    f16* orow = out + (size_t)(s * Bb + b) * Ee;
    for (int e = t; e < Ee; e += 256) orow[e] = (f16)(e0[e] + e1[e] + e2[e] + e3[e]);
}

// ---------------------------------------------------------------------------
// C[M,N] = A[M,K] @ B[N,K]^T + bias[N]  (f16 in, f16 out, fp32 accum)
#define BM 128
#define BN 128
#define BK 32
#define LDP 40

__global__ __launch_bounds__(256) void gemm_bt_kernel(
    const f16* __restrict__ A, const f16* __restrict__ Bw,
    const float* __restrict__ bias, f16* __restrict__ C,
    int M, int N, int K)
{
    __shared__ f16 As[BM * LDP];
    __shared__ f16 Bs[BN * LDP];
    int tid  = threadIdx.x;
    int n0   = blockIdx.x * BN;
    int m0   = blockIdx.y * BM;
    int w    = tid >> 6, lane = tid & 63;
    int wm   = (w >> 1) * 64, wn = (w & 1) * 64;
    int lrow = lane & 15, koff = lane >> 4;

    f32x4 acc[4][4] = {};

    for (int kb = 0; kb < K; kb += BK) {
        __syncthreads();
        #pragma unroll
        for (int h = 0; h < 2; ++h) {
            int ch  = tid + h * 256;
            int row = ch >> 2;
            int cc  = (ch & 3) * 8;
            *reinterpret_cast<uint4*>(&As[row * LDP + cc]) =
                *reinterpret_cast<const uint4*>(A + (size_t)(m0 + row) * K + kb + cc);
            *reinterpret_cast<uint4*>(&Bs[row * LDP + cc]) =
                *reinterpret_cast<const uint4*>(Bw + (size_t)(n0 + row) * K + kb + cc);
        }
        __syncthreads();
        half8 af[4], bf[4];
        #pragma unroll
        for (int mt = 0; mt < 4; ++mt)
            af[mt] = *reinterpret_cast<const half8*>(&As[(wm + mt * 16 + lrow) * LDP + koff * 8]);
        #pragma unroll
        for (int nt = 0; nt < 4; ++nt)
            bf[nt] = *reinterpret_cast<const half8*>(&Bs[(wn + nt * 16 + lrow) * LDP + koff * 8]);
        #pragma unroll
        for (int mt = 0; mt < 4; ++mt)
            #pragma unroll
            for (int nt = 0; nt < 4; ++nt)
                acc[mt][nt] = __builtin_amdgcn_mfma_f32_16x16x32_f16(af[mt], bf[nt], acc[mt][nt], 0, 0, 0);
    }

    #pragma unroll
    for (int mt = 0; mt < 4; ++mt)
        #pragma unroll
        for (int nt = 0; nt < 4; ++nt) {
            int col = n0 + wn + nt * 16 + lrow;
            float bv = bias[col];
            #pragma unroll
            for (int r = 0; r < 4; ++r) {
                int rowg = m0 + wm + mt * 16 + koff * 4 + r;
                C[(size_t)rowg * N + col] = (f16)(acc[mt][nt][r] + bv);
            }
        }
}

// ---------------------------------------------------------------------------
// Grid barrier: one relaxed RMW arrival per WG; waiters poll an epoch flag
// with acquire atomic LOADS (no RMW serialization). Flag on its own line.
__device__ __forceinline__ void grid_sync(unsigned* bar, unsigned epoch) {
    __syncthreads();
    if (threadIdx.x == 0) {
        __threadfence();
        unsigned prev = __hip_atomic_fetch_add(&bar[0], 1u, __ATOMIC_RELAXED,
                                               __HIP_MEMORY_SCOPE_AGENT);
        if (prev == epoch * NBLK - 1u) {
            __hip_atomic_store(&bar[32], epoch, __ATOMIC_RELEASE,
                               __HIP_MEMORY_SCOPE_AGENT);
        } else {
            unsigned v;
            do {
                __builtin_amdgcn_s_sleep(1);
                v = __hip_atomic_load(&bar[32], __ATOMIC_ACQUIRE,
                                      __HIP_MEMORY_SCOPE_AGENT);
            } while (v < epoch);
        }
        __threadfence();
    }
    __syncthreads();
}

__device__ __forceinline__ float sigm(float v) { return 1.f / (1.f + __expf(-v)); }

// ---------------------------------------------------------------------------
// Persistent fused 2-layer LSTM scan, 96 WGs x 512 threads.
// WGs 0..31:  L0, 32 units each; wave (g=w>>1, ch=w&1): 16 cols, K=1024.
// WGs 32..95: L1, 16 units each; wave (g=w&3, ksec=w>>2): 16 cols, K=1024 half.
// Weights in VGPRs; h staged via reg-primed double-buffered LDS; grid barrier/step.
__global__ __launch_bounds__(512, 2) void scan_kernel(
    const f16* __restrict__ gx0, int t_begin, int t_end,
    const f16* __restrict__ wih1, const f16* __restrict__ whh0,
    const f16* __restrict__ whh1, const float* __restrict__ bias1,
    f16* __restrict__ h0a, f16* __restrict__ h0b,
    f16* __restrict__ h1a, f16* __restrict__ h1b,
    float* __restrict__ c0, float* __restrict__ c1,
    float* __restrict__ out, unsigned* __restrict__ bar)
{
    __shared__ __align__(16) char smem[139264];
    f16*   sb = (f16*)smem;
    float* ef = (float*)smem;

    const int tid  = threadIdx.x;
    const int wg   = blockIdx.x;
    const int lane = tid & 63;
    const int lrow = lane & 15, koff = lane >> 4;
    const int w    = tid >> 6;

    if (wg < 32) {
        // ================= Layer 0 =================
        const int u0 = wg * 32;
        const int g  = w >> 1, ch = w & 1;
        half8 wreg[32];
        {
            const f16* wr = whh0 + (size_t)(g * Hh + u0 + ch * 16 + lrow) * Hh + koff * 8;
            #pragma unroll
            for (int kt = 0; kt < 32; ++kt) wreg[kt] = *(const half8*)(wr + kt * 32);
        }
        float creg[8];
        #pragma unroll
        for (int q = 0; q < 8; ++q) {
            int p = tid + q * 512, row = p >> 5, uu = p & 31;
            creg[q] = c0[row * Hh + u0 + uu];
        }
        const int r_st = tid >> 2, qt = tid & 3;  // staging: 128B per thread

        for (int i = t_begin; i < t_end; ++i) {
            if (i < 256) {
                const f16* hp = (i & 1) ? h0a : h0b;
                f16*       hw = (i & 1) ? h0b : h0a;
                const f16* gx = gx0 + (size_t)(i - t_begin) * (Bb * FourH);
                // prefetch gx for epilogue (latency hidden across chunk loop)
                f16 gxr[8][4];
                #pragma unroll
                for (int q = 0; q < 8; ++q) {
                    int p = tid + q * 512, row = p >> 5, uu = p & 31;
                    #pragma unroll
                    for (int gg = 0; gg < 4; ++gg)
                        gxr[q][gg] = gx[(size_t)row * FourH + gg * Hh + u0 + uu];
                }
                f32x4 acc[8] = {};
                // prime chunk 0 into registers
                uint4 sreg[8];
                {
                    const f16* gsrc = hp + (size_t)r_st * Hh + qt * 64;
                    #pragma unroll
                    for (int ii = 0; ii < 8; ++ii) sreg[ii] = *(const uint4*)(gsrc + ii * 8);
                }
                #pragma unroll
                for (int ck = 0; ck < 4; ++ck) {
                    f16* buf = sb + (ck & 1) * 33792;      // 128 x 264
                    __syncthreads();                        // buf free (readers of ck-2 done)
                    {
                        f16* dst = buf + r_st * 264 + qt * 64;
                        #pragma unroll
                        for (int ii = 0; ii < 8; ++ii) *(uint4*)(dst + ii * 8) = sreg[ii];
                    }
                    __syncthreads();                        // staged data visible
                    if (ck < 3) {                           // issue next chunk's loads early
                        const f16* gsrc = hp + (size_t)r_st * Hh + (ck + 1) * 256 + qt * 64;
                        #pragma unroll
                        for (int ii = 0; ii < 8; ++ii) sreg[ii] = *(const uint4*)(gsrc + ii * 8);
                    }
                    #pragma unroll
                    for (int kt = 0; kt < 8; ++kt)
                        #pragma unroll
                        for (int mt = 0; mt < 8; ++mt) {
                            half8 a = *(const half8*)(buf + (mt * 16 + lrow) * 264 + kt * 32 + koff * 8);
                            acc[mt] = __builtin_amdgcn_mfma_f32_16x16x32_f16(a, wreg[ck * 8 + kt], acc[mt], 0, 0, 0);
                        }
                }
                // epilogue: exchange via ef (reuses buf[0]; all waves past buf[0] reads)
                #pragma unroll
                for (int mt = 0; mt < 8; ++mt)
                    #pragma unroll
                    for (int r = 0; r < 4; ++r)
                        ef[(mt * 16 + koff * 4 + r) * 132 + g * 32 + ch * 16 + lrow] = acc[mt][r];
                __syncthreads();
                #pragma unroll
                for (int q = 0; q < 8; ++q) {
                    int p = tid + q * 512, row = p >> 5, uu = p & 31;
                    float ip = ef[row * 132 +       uu] + (float)gxr[q][0];
                    float fp = ef[row * 132 +  32 + uu] + (float)gxr[q][1];
                    float gp = ef[row * 132 +  64 + uu] + (float)gxr[q][2];
                    float op = ef[row * 132 +  96 + uu] + (float)gxr[q][3];
                    float cn = sigm(fp) * creg[q] + sigm(ip) * tanhf(gp);
                    creg[q] = cn;
                    hw[row * Hh + u0 + uu] = (f16)(sigm(op) * tanhf(cn));
                }
            }
            if (i + 1 < t_end) grid_sync(bar, (unsigned)(i - t_begin + 1));
        }
        #pragma unroll
        for (int q = 0; q < 8; ++q) {
            int p = tid + q * 512, row = p >> 5, uu = p & 31;
            c0[row * Hh + u0 + uu] = creg[q];
        }
    } else {
        // ================= Layer 1 (K = 2048: [wih1 | whh1]) =================
        const int u0   = (wg - 32) * 16;
        const int g    = w & 3, ksec = w >> 2;
        half8 wreg[32];
        {
            const f16* wr = (ksec ? whh1 : wih1) + (size_t)(g * Hh + u0 + lrow) * Hh + koff * 8;
            #pragma unroll
            for (int kt = 0; kt < 32; ++kt) wreg[kt] = *(const half8*)(wr + kt * 32);
        }
        const int uuc = tid & 15;
        float b1r[4];
        #pragma unroll
        for (int gg = 0; gg < 4; ++gg) b1r[gg] = bias1[gg * Hh + u0 + uuc];
        float creg[4];
        #pragma unroll
        for (int q = 0; q < 4; ++q) {
            int p = tid + q * 512, row = p >> 4;
            creg[q] = c1[row * Hh + u0 + uuc];
        }
        const int mat_s = tid >> 8, r_s = (tid >> 1) & 127, hf = tid & 1;

        for (int i = t_begin; i < t_end; ++i) {
            int t1 = i - 1;
            if (t1 >= 0) {
                const f16* a0 = (t1 & 1) ? h0b : h0a;   // h0[t1]
                const f16* a1 = (t1 & 1) ? h1a : h1b;   // h1[t1-1]
                f16*       hw = (t1 & 1) ? h1b : h1a;   // h1[t1]
                const f16* m0p = mat_s ? a1 : a0;
                f32x4 acc[8] = {};
                uint4 sreg[8];
                {
                    const f16* gsrc = m0p + (size_t)r_s * Hh + hf * 64;
                    #pragma unroll
                    for (int ii = 0; ii < 8; ++ii) sreg[ii] = *(const uint4*)(gsrc + ii * 8);
                }
                #pragma unroll
                for (int ck = 0; ck < 8; ++ck) {
                    f16* buf = sb + (ck & 1) * 34816;      // [2 mats][128 x 136]
                    __syncthreads();
                    {
                        f16* dst = buf + mat_s * 17408 + r_s * 136 + hf * 64;
                        #pragma unroll
                        for (int ii = 0; ii < 8; ++ii) *(uint4*)(dst + ii * 8) = sreg[ii];
                    }
                    __syncthreads();
                    if (ck < 7) {
                        const f16* gsrc = m0p + (size_t)r_s * Hh + (ck + 1) * 128 + hf * 64;
                        #pragma unroll
                        for (int ii = 0; ii < 8; ++ii) sreg[ii] = *(const uint4*)(gsrc + ii * 8);
                    }
                    #pragma unroll
                    for (int kt = 0; kt < 4; ++kt)
                        #pragma unroll
                        for (int mt = 0; mt < 8; ++mt) {
                            half8 a = *(const half8*)(buf + ksec * 17408 + (mt * 16 + lrow) * 136 + kt * 32 + koff * 8);
                            acc[mt] = __builtin_amdgcn_mfma_f32_16x16x32_f16(a, wreg[ck * 4 + kt], acc[mt], 0, 0, 0);
                        }
                }
                #pragma unroll
                for (int mt = 0; mt < 8; ++mt)
                    #pragma unroll
                    for (int r = 0; r < 4; ++r)
                        ef[ksec * 8704 + (mt * 16 + koff * 4 + r) * 68 + g * 16 + lrow] = acc[mt][r];
                __syncthreads();
                #pragma unroll
                for (int q = 0; q < 4; ++q) {
                    int p = tid + q * 512, row = p >> 4;
                    float ip = ef[row * 68 +      uuc] + ef[8704 + row * 68 +      uuc] + b1r[0];
                    float fp = ef[row * 68 + 16 + uuc] + ef[8704 + row * 68 + 16 + uuc] + b1r[1];
                    float gp = ef[row * 68 + 32 + uuc] + ef[8704 + row * 68 + 32 + uuc] + b1r[2];
                    float op = ef[row * 68 + 48 + uuc] + ef[8704 + row * 68 + 48 + uuc] + b1r[3];
                    float cn = sigm(fp) * creg[q] + sigm(ip) * tanhf(gp);
                    creg[q] = cn;
                    float hn = sigm(op) * tanhf(cn);
                    hw[row * Hh + u0 + uuc] = (f16)hn;
                    out[(size_t)row * (Ss * Hh) + (size_t)t1 * Hh + u0 + uuc] = hn;
                }
            }
            if (i + 1 < t_end) grid_sync(bar, (unsigned)(i - t_begin + 1));
        }
        #pragma unroll
        for (int q = 0; q < 4; ++q) {
            int p = tid + q * 512, row = p >> 4;
            c1[row * Hh + u0 + uuc] = creg[q];
        }
    }
}

// ---------------------------------------------------------------------------
extern "C" void kernel_launch(void* const* d_in, const int* in_sizes, int n_in,
                              void* d_out, int out_size, void* d_ws, size_t ws_size,
                              hipStream_t stream) {
    const int*   x      = (const int*)  d_in[0];
    const float* emb    = (const float*)d_in[1];
    const float* proj_w = (const float*)d_in[2];
    const float* proj_b = (const float*)d_in[3];
    const float* W_ih0  = (const float*)d_in[4];
    const float* W_hh0  = (const float*)d_in[5];
    const float* b_ih0  = (const float*)d_in[6];
    const float* b_hh0  = (const float*)d_in[7];
    const float* W_ih1  = (const float*)d_in[8];
    const float* W_hh1  = (const float*)d_in[9];
    const float* b_ih1  = (const float*)d_in[10];
    const float* b_hh1  = (const float*)d_in[11];
    float* out = (float*)d_out;

    char* ws = (char*)d_ws;
    f16* emb_sum = (f16*)(ws);                               // 32 MB [S,B,E]
    f16* x_in    = (f16*)(ws + 33554432ull);                 // 32 MB [S,B,E]
    f16* gates   = (f16*)(ws + 67108864ull);                 // 128 MB (128-step chunk)
    char* wp     = ws + 201326592ull;
    f16* pw_f   = (f16*)wp; wp += (size_t)Ee * Ee * 2;
    f16* wih0_f = (f16*)wp; wp += (size_t)FourH * Ee * 2;
    f16* whh0_f = (f16*)wp; wp += (size_t)FourH * Hh * 2;
    f16* wih1_f = (f16*)wp; wp += (size_t)FourH * Hh * 2;
    f16* whh1_f = (f16*)wp; wp += (size_t)FourH * Hh * 2;
    float* bias0 = (float*)wp; wp += FourH * 4;
    float* bias1 = (float*)wp; wp += FourH * 4;
    char* zbase = wp;
    f16*   h0a = (f16*)wp;   wp += (size_t)Bb * Hh * 2;
    f16*   h0b = (f16*)wp;   wp += (size_t)Bb * Hh * 2;
    f16*   h1a = (f16*)wp;   wp += (size_t)Bb * Hh * 2;
    f16*   h1b = (f16*)wp;   wp += (size_t)Bb * Hh * 2;
    float* c0  = (float*)wp; wp += (size_t)Bb * Hh * 4;
    float* c1  = (float*)wp; wp += (size_t)Bb * Hh * 4;
    unsigned* bar = (unsigned*)wp; wp += 256;
    size_t zbytes = (size_t)(wp - zbase);

    cvt_f16_kernel<<<512, 256, 0, stream>>>(proj_w, pw_f,   Ee * Ee);
    cvt_f16_kernel<<<512, 256, 0, stream>>>(W_ih0,  wih0_f, FourH * Ee);
    cvt_f16_kernel<<<512, 256, 0, stream>>>(W_hh0,  whh0_f, FourH * Hh);
    cvt_f16_kernel<<<512, 256, 0, stream>>>(W_ih1,  wih1_f, FourH * Hh);
    cvt_f16_kernel<<<512, 256, 0, stream>>>(W_hh1,  whh1_f, FourH * Hh);
    bias_combine_kernel<<<32, 256, 0, stream>>>(b_ih0, b_hh0, b_ih1, b_hh1, bias0, bias1);
    hipMemsetAsync(zbase, 0, zbytes, stream);

    emb_kernel<<<Mrows, 256, 0, stream>>>(x, emb, emb_sum);
    gemm_bt_kernel<<<dim3(Ee / BN, Mrows / BM), 256, 0, stream>>>(
        emb_sum, pw_f, proj_b, x_in, Mrows, Ee, Ee);

    const int CM = Mrows / 2;   // 16384 rows = 128 steps (time-major)
    for (int half = 0; half < 2; ++half) {
        gemm_bt_kernel<<<dim3(FourH / BN, CM / BM), 256, 0, stream>>>(
            x_in + (size_t)half * CM * Ee, wih0_f, bias0, gates, CM, FourH, Ee);
        if (half) hipMemsetAsync(bar, 0, 256, stream);
        int tb = half * 128;
        int te = (half == 0) ? 128 : 257;
        const f16* gxp = gates;
        void* args[] = { (void*)&gxp, (void*)&tb, (void*)&te,
                         (void*)&wih1_f, (void*)&whh0_f, (void*)&whh1_f, (void*)&bias1,
                         (void*)&h0a, (void*)&h0b, (void*)&h1a, (void*)&h1b,
                         (void*)&c0, (void*)&c1, (void*)&out, (void*)&bar };
        hipLaunchCooperativeKernel((const void*)scan_kernel, dim3(NBLK), dim3(512),
                                   args, 0, stream);
    }
}